// Round 2
// baseline (453.482 us; speedup 1.0000x reference)
//
#include <hip/hip_runtime.h>

#define SCALE_F 512.0f

// ws layout (float offsets)
#define WS_H     0        // B*S*E = 131072 floats
#define WS_GSUM  131072   // 32 floats

// ---------------- Kernel 1: h[b,s,e] for all 8 experts + gate-logit partial sums
// grid 4096 blocks x 256 thr; 4 tokens/block (16KB LDS); wave w owns weight rows 4w..4w+3
// rows 0..7 = lora_A experts, rows 8..15 = gate_w experts
__global__ __launch_bounds__(256) void k1_h_gate(
    const float* __restrict__ x, const float* __restrict__ lora_A,
    const float* __restrict__ gate_w, float* __restrict__ h,
    float* __restrict__ gsum)
{
    const int tid  = threadIdx.x;
    const int w    = tid >> 6;
    const int lane = tid & 63;
    const int tok0 = blockIdx.x * 4;       // global token base
    const int b    = tok0 >> 12;           // token/4096

    __shared__ float xbuf[4 * 1024];       // 4 token rows, 16 KB

    // Wave's 4 weight rows in registers: 16 floats/lane/row at float4 idx lane+64j.
    float4 W[4][4];
#pragma unroll
    for (int rr = 0; rr < 4; ++rr) {
        const int row = 4 * w + rr;
        const float* rp = (row < 8) ? (lora_A + row * 1024)
                                    : (gate_w + (row - 8) * 1024);
        const float4* rp4 = (const float4*)rp;
#pragma unroll
        for (int j = 0; j < 4; ++j) W[rr][j] = rp4[lane + 64 * j];
    }

    // stage 4 token rows = 1024 float4, coalesced
    const float4* src = (const float4*)(x + (size_t)tok0 * 1024);
    float4* dst = (float4*)xbuf;
#pragma unroll
    for (int j = 0; j < 4; ++j) dst[tid + 256 * j] = src[tid + 256 * j];
    __syncthreads();

    float gacc0 = 0.f, gacc1 = 0.f, gacc2 = 0.f, gacc3 = 0.f;

#pragma unroll 2
    for (int t = 0; t < 4; ++t) {
        const float4* xr = (const float4*)(xbuf + t * 1024);
        const float4 xv0 = xr[lane];
        const float4 xv1 = xr[lane + 64];
        const float4 xv2 = xr[lane + 128];
        const float4 xv3 = xr[lane + 192];

        float p[4];
#pragma unroll
        for (int rr = 0; rr < 4; ++rr) {
            const float4 a0 = W[rr][0], a1 = W[rr][1];
            const float4 a2 = W[rr][2], a3 = W[rr][3];
            float s;
            s  = xv0.x * a0.x + xv0.y * a0.y + xv0.z * a0.z + xv0.w * a0.w;
            s += xv1.x * a1.x + xv1.y * a1.y + xv1.z * a1.z + xv1.w * a1.w;
            s += xv2.x * a2.x + xv2.y * a2.y + xv2.z * a2.z + xv2.w * a2.w;
            s += xv3.x * a3.x + xv3.y * a3.y + xv3.z * a3.z + xv3.w * a3.w;
            p[rr] = s;
        }
        // butterfly: all lanes end with full sums
#pragma unroll
        for (int off = 32; off > 0; off >>= 1) {
            p[0] += __shfl_xor(p[0], off);
            p[1] += __shfl_xor(p[1], off);
            p[2] += __shfl_xor(p[2], off);
            p[3] += __shfl_xor(p[3], off);
        }
        const int tok = tok0 + t;
        if (w < 2) {
            if (lane == 0) {
                float4 hv = make_float4(p[0], p[1], p[2], p[3]);
                *(float4*)(h + (size_t)tok * 8 + w * 4) = hv;
            }
        } else {
            gacc0 += p[0]; gacc1 += p[1]; gacc2 += p[2]; gacc3 += p[3];
        }
    }

    if (w >= 2 && lane == 0) {
        float* g = gsum + b * 8 + (w - 2) * 4;
        atomicAdd(g + 0, gacc0);
        atomicAdd(g + 1, gacc1);
        atomicAdd(g + 2, gacc2);
        atomicAdd(g + 3, gacc3);
    }
}

// ---------------- Kernel 3 (gating fused): out[tok,o] = c0*h0*B[i0,o] + c1*h1*B[i1,o]
// grid 2048 blocks x 256 thr; 8 tokens/block; per-thread redundant softmax/top-2
__global__ __launch_bounds__(256) void k3_combine(
    const float* __restrict__ h, const float* __restrict__ gsum,
    const float* __restrict__ gate_b, const float* __restrict__ lora_B,
    float* __restrict__ out)
{
    const int tid = threadIdx.x;
    const int blk = blockIdx.x;
    const int b   = blk >> 9;                 // 512 blocks per batch

    // redundant per-thread gating (gsum/gate_b broadcast-cached)
    float sc[8];
    float m = -1e30f;
#pragma unroll
    for (int e = 0; e < 8; ++e) {
        sc[e] = gsum[b * 8 + e] * (1.0f / 4096.0f) + gate_b[e];
        m = fmaxf(m, sc[e]);
    }
    float sum = 0.f;
#pragma unroll
    for (int e = 0; e < 8; ++e) { sc[e] = __expf(sc[e] - m); sum += sc[e]; }
    const float inv = 1.0f / sum;

    int i0 = 0;
#pragma unroll
    for (int e = 1; e < 8; ++e) if (sc[e] > sc[i0]) i0 = e;
    int i1 = (i0 == 0) ? 1 : 0;
#pragma unroll
    for (int e = 0; e < 8; ++e) if (e != i0 && sc[e] > sc[i1]) i1 = e;

    const float c0 = SCALE_F * sc[i0] * inv;
    const float c1 = SCALE_F * sc[i1] * inv;

    const float4 b0 = ((const float4*)(lora_B + i0 * 1024))[tid];
    const float4 b1 = ((const float4*)(lora_B + i1 * 1024))[tid];
    const float4 v0 = make_float4(c0 * b0.x, c0 * b0.y, c0 * b0.z, c0 * b0.w);
    const float4 v1 = make_float4(c1 * b1.x, c1 * b1.y, c1 * b1.z, c1 * b1.w);

    const int tok0 = blk * 8;
    float4* out4 = (float4*)out;
#pragma unroll
    for (int t = 0; t < 8; ++t) {
        const int tok = tok0 + t;
        const float h0 = h[tok * 8 + i0];
        const float h1 = h[tok * 8 + i1];
        float4 r;
        r.x = h0 * v0.x + h1 * v1.x;
        r.y = h0 * v0.y + h1 * v1.y;
        r.z = h0 * v0.z + h1 * v1.z;
        r.w = h0 * v0.w + h1 * v1.w;
        out4[(size_t)tok * 256 + tid] = r;
    }
}

extern "C" void kernel_launch(void* const* d_in, const int* in_sizes, int n_in,
                              void* d_out, int out_size, void* d_ws, size_t ws_size,
                              hipStream_t stream) {
    const float* x      = (const float*)d_in[0];
    const float* lora_A = (const float*)d_in[1];
    const float* lora_B = (const float*)d_in[2];
    const float* gate_w = (const float*)d_in[3];
    const float* gate_b = (const float*)d_in[4];
    float* out = (float*)d_out;

    float* ws   = (float*)d_ws;
    float* h    = ws + WS_H;
    float* gsum = ws + WS_GSUM;

    hipMemsetAsync(gsum, 0, 32 * sizeof(float), stream);
    k1_h_gate<<<4096, 256, 0, stream>>>(x, lora_A, gate_w, h, gsum);
    k3_combine<<<2048, 256, 0, stream>>>(h, gsum, gate_b, lora_B, out);
}

// Round 3
// 137.942 us; speedup vs baseline: 3.2875x; 3.2875x over previous
//
#include <hip/hip_runtime.h>

#define SCALE_F 512.0f

// ws layout (float offsets)
#define WS_H     0        // B*S*E = 131072 floats
#define WS_GPART 131072   // 2048 blocks * 8 experts = 16384 floats
#define WS_SELC  147456   // 8 ints (sel) + 8 floats (coef)

// ---------------- Kernel 1: h[b,s,e] for all 8 experts + per-block gate partials
// grid 2048 blocks x 256 thr; 8 tokens/block (32KB LDS); wave w owns weight rows 4w..4w+3
// rows 0..7 = lora_A experts, rows 8..15 = gate_w experts. NO atomics.
__global__ __launch_bounds__(256) void k1_h_gate(
    const float* __restrict__ x, const float* __restrict__ lora_A,
    const float* __restrict__ gate_w, float* __restrict__ h,
    float* __restrict__ gpart)
{
    const int tid  = threadIdx.x;
    const int w    = tid >> 6;
    const int lane = tid & 63;
    const int tok0 = blockIdx.x * 8;       // global token base

    __shared__ float xbuf[8 * 1024];       // 8 token rows, 32 KB

    // Wave's 4 weight rows in registers: 16 floats/lane/row at float4 idx lane+64j.
    float4 W[4][4];
#pragma unroll
    for (int rr = 0; rr < 4; ++rr) {
        const int row = 4 * w + rr;
        const float* rp = (row < 8) ? (lora_A + row * 1024)
                                    : (gate_w + (row - 8) * 1024);
        const float4* rp4 = (const float4*)rp;
#pragma unroll
        for (int j = 0; j < 4; ++j) W[rr][j] = rp4[lane + 64 * j];
    }

    // stage 8 token rows = 2048 float4, coalesced
    const float4* src = (const float4*)(x + (size_t)tok0 * 1024);
    float4* dst = (float4*)xbuf;
#pragma unroll
    for (int j = 0; j < 8; ++j) dst[tid + 256 * j] = src[tid + 256 * j];
    __syncthreads();

    float gacc0 = 0.f, gacc1 = 0.f, gacc2 = 0.f, gacc3 = 0.f;

#pragma unroll 2
    for (int t = 0; t < 8; ++t) {
        const float4* xr = (const float4*)(xbuf + t * 1024);
        const float4 xv0 = xr[lane];
        const float4 xv1 = xr[lane + 64];
        const float4 xv2 = xr[lane + 128];
        const float4 xv3 = xr[lane + 192];

        float p[4];
#pragma unroll
        for (int rr = 0; rr < 4; ++rr) {
            const float4 a0 = W[rr][0], a1 = W[rr][1];
            const float4 a2 = W[rr][2], a3 = W[rr][3];
            float s;
            s  = xv0.x * a0.x + xv0.y * a0.y + xv0.z * a0.z + xv0.w * a0.w;
            s += xv1.x * a1.x + xv1.y * a1.y + xv1.z * a1.z + xv1.w * a1.w;
            s += xv2.x * a2.x + xv2.y * a2.y + xv2.z * a2.z + xv2.w * a2.w;
            s += xv3.x * a3.x + xv3.y * a3.y + xv3.z * a3.z + xv3.w * a3.w;
            p[rr] = s;
        }
        // butterfly: all lanes end with full sums
#pragma unroll
        for (int off = 32; off > 0; off >>= 1) {
            p[0] += __shfl_xor(p[0], off);
            p[1] += __shfl_xor(p[1], off);
            p[2] += __shfl_xor(p[2], off);
            p[3] += __shfl_xor(p[3], off);
        }
        const int tok = tok0 + t;
        if (w < 2) {
            if (lane == 0) {
                float4 hv = make_float4(p[0], p[1], p[2], p[3]);
                *(float4*)(h + (size_t)tok * 8 + w * 4) = hv;
            }
        } else {
            gacc0 += p[0]; gacc1 += p[1]; gacc2 += p[2]; gacc3 += p[3];
        }
    }

    // per-block gate partials: distinct slots, no contention
    if (w >= 2 && lane == 0) {
        float4 gv = make_float4(gacc0, gacc1, gacc2, gacc3);
        *(float4*)(gpart + (size_t)blockIdx.x * 8 + (w - 2) * 4) = gv;
    }
}

// ---------------- Kernel 2: reduce gate partials, softmax, top-2 -> sel/coef
// 1 block x 256 thr. 32 (b,e) pairs x 8 threads each, 64 values per thread.
__global__ __launch_bounds__(256) void k2_gate(
    const float* __restrict__ gpart, const float* __restrict__ gate_b,
    int* __restrict__ sel, float* __restrict__ coef)
{
    const int tid  = threadIdx.x;
    const int j    = tid & 7;        // 0..7
    const int pair = tid >> 3;       // 0..31
    const int b    = pair >> 3;      // 0..3
    const int e    = pair & 7;       // 0..7

    __shared__ float s_red[32][8];
    __shared__ float s_logit[32];

    float acc = 0.f;
#pragma unroll 8
    for (int k = 0; k < 64; ++k) {
        acc += gpart[(size_t)(b * 512 + j * 64 + k) * 8 + e];
    }
    s_red[pair][j] = acc;
    __syncthreads();

    if (j == 0) {
        float s = 0.f;
#pragma unroll
        for (int q = 0; q < 8; ++q) s += s_red[pair][q];
        s_logit[pair] = s * (1.0f / 4096.0f) + gate_b[e];
    }
    __syncthreads();

    if (tid < 4) {
        float sc[8];
        float m = -1e30f;
#pragma unroll
        for (int q = 0; q < 8; ++q) { sc[q] = s_logit[tid * 8 + q]; m = fmaxf(m, sc[q]); }
        float sum = 0.f;
#pragma unroll
        for (int q = 0; q < 8; ++q) { sc[q] = __expf(sc[q] - m); sum += sc[q]; }
        const float inv = 1.0f / sum;

        int i0 = 0;
#pragma unroll
        for (int q = 1; q < 8; ++q) if (sc[q] > sc[i0]) i0 = q;
        int i1 = (i0 == 0) ? 1 : 0;
#pragma unroll
        for (int q = 0; q < 8; ++q) if (q != i0 && sc[q] > sc[i1]) i1 = q;

        sel[tid * 2]      = i0;
        sel[tid * 2 + 1]  = i1;
        coef[tid * 2]     = SCALE_F * sc[i0] * inv;
        coef[tid * 2 + 1] = SCALE_F * sc[i1] * inv;
    }
}

// ---------------- Kernel 3: out[tok,o] = c0*h0*B[i0,o] + c1*h1*B[i1,o]
// grid 2048 blocks x 256 thr; 8 tokens/block; v0/v1 float4 held in registers
__global__ __launch_bounds__(256) void k3_combine(
    const float* __restrict__ h, const int* __restrict__ sel,
    const float* __restrict__ coef, const float* __restrict__ lora_B,
    float* __restrict__ out)
{
    const int tid = threadIdx.x;
    const int blk = blockIdx.x;
    const int b   = blk >> 9;                 // 512 blocks per batch

    const int   i0 = sel[b * 2];
    const int   i1 = sel[b * 2 + 1];
    const float c0 = coef[b * 2];
    const float c1 = coef[b * 2 + 1];

    const float4 b0 = ((const float4*)(lora_B + i0 * 1024))[tid];
    const float4 b1 = ((const float4*)(lora_B + i1 * 1024))[tid];
    const float4 v0 = make_float4(c0 * b0.x, c0 * b0.y, c0 * b0.z, c0 * b0.w);
    const float4 v1 = make_float4(c1 * b1.x, c1 * b1.y, c1 * b1.z, c1 * b1.w);

    const int tok0 = blk * 8;
    float4* out4 = (float4*)out;
#pragma unroll
    for (int t = 0; t < 8; ++t) {
        const int tok = tok0 + t;
        const float h0 = h[tok * 8 + i0];
        const float h1 = h[tok * 8 + i1];
        float4 r;
        r.x = h0 * v0.x + h1 * v1.x;
        r.y = h0 * v0.y + h1 * v1.y;
        r.z = h0 * v0.z + h1 * v1.z;
        r.w = h0 * v0.w + h1 * v1.w;
        out4[(size_t)tok * 256 + tid] = r;
    }
}

extern "C" void kernel_launch(void* const* d_in, const int* in_sizes, int n_in,
                              void* d_out, int out_size, void* d_ws, size_t ws_size,
                              hipStream_t stream) {
    const float* x      = (const float*)d_in[0];
    const float* lora_A = (const float*)d_in[1];
    const float* lora_B = (const float*)d_in[2];
    const float* gate_w = (const float*)d_in[3];
    const float* gate_b = (const float*)d_in[4];
    float* out = (float*)d_out;

    float* ws    = (float*)d_ws;
    float* h     = ws + WS_H;
    float* gpart = ws + WS_GPART;
    int*   sel   = (int*)(ws + WS_SELC);
    float* coef  = ws + WS_SELC + 8;

    k1_h_gate<<<2048, 256, 0, stream>>>(x, lora_A, gate_w, h, gpart);
    k2_gate<<<1, 256, 0, stream>>>(gpart, gate_b, sel, coef);
    k3_combine<<<2048, 256, 0, stream>>>(h, sel, coef, lora_B, out);
}